// Round 4
// baseline (62.792 us; speedup 1.0000x reference)
//
#include <hip/hip_runtime.h>
#include <hip/hip_bf16.h>

typedef __attribute__((ext_vector_type(8))) short short8;
typedef __attribute__((ext_vector_type(4))) short short4v;
typedef __attribute__((ext_vector_type(4))) _Float16 half4;
typedef __attribute__((ext_vector_type(4))) float f32x4;

#define SPW 16384   // T*H*W spatial positions per batch
#define XST 72      // Xl row stride in shorts: 16B-aligned rows, even bank coverage
#define RP  68      // epilogue reduce buffer row stride (dwords)
#define LOG2E 1.4426950408889634f

__device__ __forceinline__ float exp2_hw(float f) {
  return __builtin_amdgcn_exp2f(f);   // v_exp_f32 (base-2)
}

__device__ __forceinline__ short bf16s(float f) {
  union { __hip_bfloat16 h; short s; } u;
  u.h = __float2bfloat16(f);
  return u.s;
}

// ---------------- merged prep kernel ----------------
// f <  4096  : a1 frags (16x16x32 A) of (-2*log2e)*E
// f < 12288  : eb frags (16x16x16 f16 B) of E
// f < 12800  : norms ||e_k||^2 * log2e
__global__ void prep_all(const float* __restrict__ emb, short8* __restrict__ a1,
                         half4* __restrict__ eb, float* __restrict__ norms) {
  const int f = blockIdx.x * 256 + threadIdx.x;
  if (f < 4096) {
    const int l = f & 63;
    const int s = (f >> 6) & 1;
    const int m = f >> 7;
    const int row = m * 16 + (l & 15);
    const int col0 = s * 32 + (l >> 4) * 8;
    short8 v;
    #pragma unroll
    for (int i = 0; i < 8; ++i)
      v[i] = bf16s(-2.0f * LOG2E * emb[row * 64 + col0 + i]);
    a1[f] = v;
  } else if (f < 12288) {
    const int e = f - 4096;
    const int l = e & 63;
    const int m2 = (e >> 6) & 3;
    const int w = (e >> 8) & 3;
    const int c = e >> 10;
    const int d = m2 * 16 + (l & 15);
    const int k0 = c * 64 + w * 16 + 4 * (l >> 4);
    half4 v;
    #pragma unroll
    for (int i = 0; i < 4; ++i) v[i] = (_Float16)emb[(k0 + i) * 64 + d];
    eb[e] = v;
  } else if (f < 12800) {
    const int k = f - 12288;
    float acc = 0.f;
    #pragma unroll
    for (int d = 0; d < 64; ++d) { float e = emb[k * 64 + d]; acc += e * e; }
    norms[k] = acc * LOG2E;
  }
}

// ---------------- main kernel ----------------
// logits(base2) = log2e*(||e_k||^2 - 2 x.e_k); ||x||^2 dropped (shift-invariant),
// |logit| tiny -> exp2 without max subtraction. Wave w owns k-slices c*64+w*16:
// matmul1 C-layout (col=l15, row=4g+r) == A-layout of mfma_16x16x16_f16, so P
// feeds matmul2 in-register; no barriers in the main loop. launch_bounds(256,4)
// caps unified VGPR+AGPR at 128 -> 4 waves/SIMD (vs 2 at R3's 144 regs).
__global__ __launch_bounds__(256, 4) void vq_main(
    const float* __restrict__ x, const short8* __restrict__ a1,
    const half4* __restrict__ eb, const float* __restrict__ norms,
    float* __restrict__ out) {
  __shared__ __align__(16) char lds_raw[18688];
  short* Xl  = reinterpret_cast<short*>(lds_raw);             // [64][72] bf16 (stage+main)
  float* Rf  = reinterpret_cast<float*>(lds_raw);             // [64][68] f32 (epilogue)
  float* denl = reinterpret_cast<float*>(lds_raw + 17408);    // [4][64]
  float* rden = reinterpret_cast<float*>(lds_raw + 18432);    // [64]

  const int t = threadIdx.x;
  const int lane = t & 63;
  const int w = t >> 6;
  const int l15 = lane & 15;
  const int g = lane >> 4;

  const int tile = blockIdx.x * 64;
  const int b = tile >> 14;
  const int off = tile & 16383;
  const float* xb = x + (size_t)b * (64 * SPW) + off;
  float* ob = out + (size_t)b * (64 * SPW) + off;

  // stage: each thread loads a 4d x 4n fp32 micro-tile (coalesced float4 rows),
  // transposes in-register, writes bf16 d-quads as ds_write_b64 into Xl[n][d].
  {
    const int n0 = 4 * (t & 15);
    const int d0 = 4 * (t >> 4);
    const float4 r0 = *reinterpret_cast<const float4*>(xb + (size_t)(d0 + 0) * SPW + n0);
    const float4 r1 = *reinterpret_cast<const float4*>(xb + (size_t)(d0 + 1) * SPW + n0);
    const float4 r2 = *reinterpret_cast<const float4*>(xb + (size_t)(d0 + 2) * SPW + n0);
    const float4 r3 = *reinterpret_cast<const float4*>(xb + (size_t)(d0 + 3) * SPW + n0);
    const short4v c0 = {bf16s(r0.x), bf16s(r1.x), bf16s(r2.x), bf16s(r3.x)};
    const short4v c1 = {bf16s(r0.y), bf16s(r1.y), bf16s(r2.y), bf16s(r3.y)};
    const short4v c2 = {bf16s(r0.z), bf16s(r1.z), bf16s(r2.z), bf16s(r3.z)};
    const short4v c3 = {bf16s(r0.w), bf16s(r1.w), bf16s(r2.w), bf16s(r3.w)};
    *reinterpret_cast<short4v*>(&Xl[(n0 + 0) * XST + d0]) = c0;
    *reinterpret_cast<short4v*>(&Xl[(n0 + 1) * XST + d0]) = c1;
    *reinterpret_cast<short4v*>(&Xl[(n0 + 2) * XST + d0]) = c2;
    *reinterpret_cast<short4v*>(&Xl[(n0 + 3) * XST + d0]) = c3;
  }
  __syncthreads();

  // bx: B-frags of matmul1, 8x ds_read_b128, persistent (32 VGPRs)
  short8 bx[4][2];
  #pragma unroll
  for (int j = 0; j < 4; ++j) {
    const int base = (j * 16 + l15) * XST + g * 8;
    bx[j][0] = *reinterpret_cast<const short8*>(&Xl[base]);
    bx[j][1] = *reinterpret_cast<const short8*>(&Xl[base + 32]);
  }

  f32x4 pacc[4][4];   // [j n-tile][m2 d-tile] partial Num^T over this wave's k-slices
  #pragma unroll
  for (int j = 0; j < 4; ++j)
    #pragma unroll
    for (int m2 = 0; m2 < 4; ++m2) pacc[j][m2] = f32x4{0.f, 0.f, 0.f, 0.f};
  float denp[4] = {0.f, 0.f, 0.f, 0.f};

  #pragma unroll 1
  for (int c = 0; c < 8; ++c) {
    const short8 a1f0 = a1[((c * 4 + w) * 2 + 0) * 64 + lane];
    const short8 a1f1 = a1[((c * 4 + w) * 2 + 1) * 64 + lane];
    const half4 ebf0 = eb[((c * 4 + w) * 4 + 0) * 64 + lane];
    const half4 ebf1 = eb[((c * 4 + w) * 4 + 1) * 64 + lane];
    const half4 ebf2 = eb[((c * 4 + w) * 4 + 2) * 64 + lane];
    const half4 ebf3 = eb[((c * 4 + w) * 4 + 3) * 64 + lane];
    const float4 nv = *reinterpret_cast<const float4*>(&norms[c * 64 + w * 16 + g * 4]);

    #pragma unroll
    for (int j = 0; j < 4; ++j) {
      f32x4 z = {0.f, 0.f, 0.f, 0.f};
      z = __builtin_amdgcn_mfma_f32_16x16x32_bf16(a1f0, bx[j][0], z, 0, 0, 0);
      z = __builtin_amdgcn_mfma_f32_16x16x32_bf16(a1f1, bx[j][1], z, 0, 0, 0);
      const float p0 = exp2_hw(nv.x + z[0]);
      const float p1 = exp2_hw(nv.y + z[1]);
      const float p2 = exp2_hw(nv.z + z[2]);
      const float p3 = exp2_hw(nv.w + z[3]);
      denp[j] += (p0 + p1) + (p2 + p3);
      const half4 pa = {(_Float16)p0, (_Float16)p1, (_Float16)p2, (_Float16)p3};
      pacc[j][0] = __builtin_amdgcn_mfma_f32_16x16x16f16(pa, ebf0, pacc[j][0], 0, 0, 0);
      pacc[j][1] = __builtin_amdgcn_mfma_f32_16x16x16f16(pa, ebf1, pacc[j][1], 0, 0, 0);
      pacc[j][2] = __builtin_amdgcn_mfma_f32_16x16x16f16(pa, ebf2, pacc[j][2], 0, 0, 0);
      pacc[j][3] = __builtin_amdgcn_mfma_f32_16x16x16f16(pa, ebf3, pacc[j][3], 0, 0, 0);
    }
  }

  // den: reduce over lane-groups (k within wave), then across waves via LDS
  #pragma unroll
  for (int j = 0; j < 4; ++j) {
    denp[j] += __shfl_xor(denp[j], 16, 64);
    denp[j] += __shfl_xor(denp[j], 32, 64);
  }
  if (lane < 16) {
    #pragma unroll
    for (int j = 0; j < 4; ++j) denl[w * 64 + j * 16 + lane] = denp[j];
  }
  __syncthreads();
  if (t < 64) {
    const float s = denl[t] + denl[64 + t] + denl[128 + t] + denl[192 + t];
    rden[t] = 1.0f / s;
  }

  // Num reduce across waves + coalesced store, one j-tile (16 n) at a time
  const int n16 = t & 15;
  const int dq2 = t >> 4;
  #pragma unroll
  for (int j = 0; j < 4; ++j) {
    __syncthreads();  // j=0: Xl dead + rden ready; j>0: WAR on Rf
    #pragma unroll
    for (int m2 = 0; m2 < 4; ++m2)
      #pragma unroll
      for (int r = 0; r < 4; ++r)
        Rf[(w * 16 + 4 * g + r) * RP + m2 * 16 + l15] = pacc[j][m2][r];
    __syncthreads();
    const float rdv = rden[j * 16 + n16];
    #pragma unroll
    for (int r = 0; r < 4; ++r) {
      const int dd = r * 16 + dq2;
      const float sum = (Rf[(n16)*RP + dd] + Rf[(16 + n16) * RP + dd])
                      + (Rf[(32 + n16) * RP + dd] + Rf[(48 + n16) * RP + dd]);
      ob[(size_t)dd * SPW + j * 16 + n16] = sum * rdv;
    }
  }
}

extern "C" void kernel_launch(void* const* d_in, const int* in_sizes, int n_in,
                              void* d_out, int out_size, void* d_ws, size_t ws_size,
                              hipStream_t stream) {
  (void)in_sizes; (void)n_in; (void)out_size; (void)ws_size;
  const float* x   = (const float*)d_in[0];   // (8, 64, 16, 32, 32) fp32
  const float* emb = (const float*)d_in[1];   // (512, 64) fp32
  float* out = (float*)d_out;

  char* ws = (char*)d_ws;
  short8* a1   = (short8*)ws;                 // 65536 B
  half4*  eb   = (half4*)(ws + 65536);        // 65536 B
  float*  norms = (float*)(ws + 131072);      // 2048 B

  prep_all<<<50, 256, 0, stream>>>(emb, a1, eb, norms);
  vq_main<<<2048, 256, 0, stream>>>(x, a1, eb, norms, out);
}

// Round 5
// 46.630 us; speedup vs baseline: 1.3466x; 1.3466x over previous
//
#include <hip/hip_runtime.h>
#include <hip/hip_bf16.h>

typedef __attribute__((ext_vector_type(8))) short short8;
typedef __attribute__((ext_vector_type(4))) short short4v;
typedef __attribute__((ext_vector_type(4))) _Float16 half4;
typedef __attribute__((ext_vector_type(4))) float f32x4;

#define SPW 16384   // T*H*W spatial positions per batch
#define XST 72      // Xl row stride in shorts (16B-aligned rows)
#define LOG2E 1.4426950408889634f

__device__ __forceinline__ float exp2_hw(float f) {
  return __builtin_amdgcn_exp2f(f);   // v_exp_f32 (base-2)
}

__device__ __forceinline__ short bf16s(float f) {
  union { __hip_bfloat16 h; short s; } u;
  u.h = __float2bfloat16(f);
  return u.s;
}

// ---------------- merged prep kernel ----------------
// f <  4096  : a1 frags (16x16x32 A) of (-2*log2e)*E
// f < 12288  : eb frags (16x16x16 f16 B) of E
// f < 12800  : norms ||e_k||^2 * log2e
__global__ void prep_all(const float* __restrict__ emb, short8* __restrict__ a1,
                         half4* __restrict__ eb, float* __restrict__ norms) {
  const int f = blockIdx.x * 256 + threadIdx.x;
  if (f < 4096) {
    const int l = f & 63;
    const int s = (f >> 6) & 1;
    const int m = f >> 7;
    const int row = m * 16 + (l & 15);
    const int col0 = s * 32 + (l >> 4) * 8;
    short8 v;
    #pragma unroll
    for (int i = 0; i < 8; ++i)
      v[i] = bf16s(-2.0f * LOG2E * emb[row * 64 + col0 + i]);
    a1[f] = v;
  } else if (f < 12288) {
    const int e = f - 4096;
    const int l = e & 63;
    const int m2 = (e >> 6) & 3;
    const int kt = e >> 8;               // k-16-tile index 0..31
    const int d = m2 * 16 + (l & 15);
    const int k0 = kt * 16 + 4 * (l >> 4);
    half4 v;
    #pragma unroll
    for (int i = 0; i < 4; ++i) v[i] = (_Float16)emb[(k0 + i) * 64 + d];
    eb[e] = v;
  } else if (f < 12800) {
    const int k = f - 12288;
    float acc = 0.f;
    #pragma unroll
    for (int d = 0; d < 64; ++d) { float e = emb[k * 64 + d]; acc += e * e; }
    norms[k] = acc * LOG2E;
  }
}

// ---------------- main kernel ----------------
// Single-wave blocks: 32 n-columns x full K=512 per wave. logits(base2) =
// log2e*(||e_k||^2 - 2 x.e_k) (||x||^2 dropped, shift-invariant; |logit| tiny ->
// exp2 without max). matmul1 C-layout (col=l15, row=4g+r) == A-layout of
// mfma_16x16x16_f16, so P feeds matmul2 in-register. No cross-wave coupling:
// den reduce is in-wave; pacc 32 AGPR + bx 16 VGPR -> 4 waves/SIMD, whole grid
// resident (4096 blocks = 16 waves/CU).
__global__ __launch_bounds__(64, 4) void vq_main(
    const float* __restrict__ x, const short8* __restrict__ a1,
    const half4* __restrict__ eb, const float* __restrict__ norms,
    float* __restrict__ out) {
  __shared__ __align__(16) short Xl[32 * XST];   // 4608 B, d-index XOR-swizzled
  __shared__ float dl[32];

  const int lane = threadIdx.x;   // 0..63
  const int l15 = lane & 15;
  const int g = lane >> 4;

  const int tile = blockIdx.x * 32;
  const int b = tile >> 14;
  const int off = tile & 16383;
  const float* xb = x + (size_t)b * (64 * SPW) + off;
  float* ob = out + (size_t)b * (64 * SPW) + off;

  // stage X tile: global [d][n] fp32 -> LDS [n][d^sw(n)] bf16.
  // Thread owns n-quad 4*(lane&7) x d-octet 8*(lane>>3); two 4x4 transposes.
  {
    const int l8 = lane & 7;
    const int lh = lane >> 3;
    const int n0 = 4 * l8;
    const int sw = l8 << 3;              // ((n>>2)&7)<<3, uniform over n0..n0+3
    #pragma unroll
    for (int h = 0; h < 2; ++h) {
      const int d0 = lh * 8 + h * 4;
      const float4 r0 = *reinterpret_cast<const float4*>(xb + (size_t)(d0 + 0) * SPW + n0);
      const float4 r1 = *reinterpret_cast<const float4*>(xb + (size_t)(d0 + 1) * SPW + n0);
      const float4 r2 = *reinterpret_cast<const float4*>(xb + (size_t)(d0 + 2) * SPW + n0);
      const float4 r3 = *reinterpret_cast<const float4*>(xb + (size_t)(d0 + 3) * SPW + n0);
      const short4v c0 = {bf16s(r0.x), bf16s(r1.x), bf16s(r2.x), bf16s(r3.x)};
      const short4v c1 = {bf16s(r0.y), bf16s(r1.y), bf16s(r2.y), bf16s(r3.y)};
      const short4v c2 = {bf16s(r0.z), bf16s(r1.z), bf16s(r2.z), bf16s(r3.z)};
      const short4v c3 = {bf16s(r0.w), bf16s(r1.w), bf16s(r2.w), bf16s(r3.w)};
      const int dsw = d0 ^ sw;           // XOR by mult of 8 keeps 4-group contiguous
      *reinterpret_cast<short4v*>(&Xl[(n0 + 0) * XST + dsw]) = c0;
      *reinterpret_cast<short4v*>(&Xl[(n0 + 1) * XST + dsw]) = c1;
      *reinterpret_cast<short4v*>(&Xl[(n0 + 2) * XST + dsw]) = c2;
      *reinterpret_cast<short4v*>(&Xl[(n0 + 3) * XST + dsw]) = c3;
    }
  }
  __syncthreads();   // single-wave: compiles to waitcnt (+barrier), ~free

  // bx: matmul1 B-frags (k=d, 8 consecutive d per lane at col n=j*16+l15)
  short8 bx[2][2];
  #pragma unroll
  for (int j = 0; j < 2; ++j) {
    const int n = j * 16 + l15;
    const int swn = ((n >> 2) & 7) << 3;
    bx[j][0] = *reinterpret_cast<const short8*>(&Xl[n * XST + ((g * 8) ^ swn)]);
    bx[j][1] = *reinterpret_cast<const short8*>(&Xl[n * XST + ((32 + g * 8) ^ swn)]);
  }

  f32x4 pacc[2][4];   // [j n-tile][m2 d-tile] Num^T accumulator (32 AGPR)
  #pragma unroll
  for (int j = 0; j < 2; ++j)
    #pragma unroll
    for (int m2 = 0; m2 < 4; ++m2) pacc[j][m2] = f32x4{0.f, 0.f, 0.f, 0.f};
  float denp[2] = {0.f, 0.f};

  for (int c = 0; c < 8; ++c) {
    #pragma unroll 2
    for (int q = 0; q < 4; ++q) {
      const int kt = c * 4 + q;          // k-16-tile index 0..31
      const short8 a1f0 = a1[(kt * 2 + 0) * 64 + lane];
      const short8 a1f1 = a1[(kt * 2 + 1) * 64 + lane];
      const half4 e0 = eb[(kt * 4 + 0) * 64 + lane];
      const half4 e1 = eb[(kt * 4 + 1) * 64 + lane];
      const half4 e2 = eb[(kt * 4 + 2) * 64 + lane];
      const half4 e3 = eb[(kt * 4 + 3) * 64 + lane];
      const float4 nv = *reinterpret_cast<const float4*>(&norms[kt * 16 + g * 4]);
      #pragma unroll
      for (int j = 0; j < 2; ++j) {
        f32x4 z = {0.f, 0.f, 0.f, 0.f};
        z = __builtin_amdgcn_mfma_f32_16x16x32_bf16(a1f0, bx[j][0], z, 0, 0, 0);
        z = __builtin_amdgcn_mfma_f32_16x16x32_bf16(a1f1, bx[j][1], z, 0, 0, 0);
        const float p0 = exp2_hw(nv.x + z[0]);
        const float p1 = exp2_hw(nv.y + z[1]);
        const float p2 = exp2_hw(nv.z + z[2]);
        const float p3 = exp2_hw(nv.w + z[3]);
        denp[j] += (p0 + p1) + (p2 + p3);
        const half4 pa = {(_Float16)p0, (_Float16)p1, (_Float16)p2, (_Float16)p3};
        pacc[j][0] = __builtin_amdgcn_mfma_f32_16x16x16f16(pa, e0, pacc[j][0], 0, 0, 0);
        pacc[j][1] = __builtin_amdgcn_mfma_f32_16x16x16f16(pa, e1, pacc[j][1], 0, 0, 0);
        pacc[j][2] = __builtin_amdgcn_mfma_f32_16x16x16f16(pa, e2, pacc[j][2], 0, 0, 0);
        pacc[j][3] = __builtin_amdgcn_mfma_f32_16x16x16f16(pa, e3, pacc[j][3], 0, 0, 0);
      }
    }
  }

  // den: in-wave reduce over lane-groups (k), then lane-transpose via tiny LDS
  #pragma unroll
  for (int j = 0; j < 2; ++j) {
    denp[j] += __shfl_xor(denp[j], 16, 64);
    denp[j] += __shfl_xor(denp[j], 32, 64);
  }
  if (lane < 16) {
    dl[lane] = denp[0];
    dl[16 + lane] = denp[1];
  }
  __syncthreads();
  const float4 dA = *reinterpret_cast<const float4*>(&dl[4 * g]);
  const float4 dB = *reinterpret_cast<const float4*>(&dl[16 + 4 * g]);
  const f32x4 rd0 = {1.0f / dA.x, 1.0f / dA.y, 1.0f / dA.z, 1.0f / dA.w};
  const f32x4 rd1 = {1.0f / dB.x, 1.0f / dB.y, 1.0f / dB.z, 1.0f / dB.w};

  // store: pacc C-layout col=d=m2*16+l15, rows = 4 consecutive n -> float4
  #pragma unroll
  for (int j = 0; j < 2; ++j) {
    const f32x4 rd = j ? rd1 : rd0;
    const int nbase = j * 16 + 4 * g;
    #pragma unroll
    for (int m2 = 0; m2 < 4; ++m2) {
      const f32x4 s = pacc[j][m2];
      const float4 o = {s[0] * rd[0], s[1] * rd[1], s[2] * rd[2], s[3] * rd[3]};
      const int d = m2 * 16 + l15;
      *reinterpret_cast<float4*>(&ob[(size_t)d * SPW + nbase]) = o;
    }
  }
}

extern "C" void kernel_launch(void* const* d_in, const int* in_sizes, int n_in,
                              void* d_out, int out_size, void* d_ws, size_t ws_size,
                              hipStream_t stream) {
  (void)in_sizes; (void)n_in; (void)out_size; (void)ws_size;
  const float* x   = (const float*)d_in[0];   // (8, 64, 16, 32, 32) fp32
  const float* emb = (const float*)d_in[1];   // (512, 64) fp32
  float* out = (float*)d_out;

  char* ws = (char*)d_ws;
  short8* a1   = (short8*)ws;                 // 65536 B
  half4*  eb   = (half4*)(ws + 65536);        // 65536 B
  float*  norms = (float*)(ws + 131072);      // 2048 B

  prep_all<<<50, 256, 0, stream>>>(emb, a1, eb, norms);
  vq_main<<<4096, 64, 0, stream>>>(x, a1, eb, norms, out);
}

// Round 6
// 45.432 us; speedup vs baseline: 1.3821x; 1.0264x over previous
//
#include <hip/hip_runtime.h>
#include <hip/hip_bf16.h>

typedef __attribute__((ext_vector_type(8))) short short8;
typedef __attribute__((ext_vector_type(4))) short short4v;
typedef __attribute__((ext_vector_type(4))) _Float16 half4;
typedef __attribute__((ext_vector_type(4))) float f32x4;

#define SPW 16384   // T*H*W spatial positions per batch
#define XST 72      // Xl row stride in shorts (16B-aligned rows)
#define RW  66      // Rf row stride in dwords
#define LOG2E 1.4426950408889634f

__device__ __forceinline__ float exp2_hw(float f) {
  return __builtin_amdgcn_exp2f(f);   // v_exp_f32 (base-2)
}

__device__ __forceinline__ short bf16s(float f) {
  union { __hip_bfloat16 h; short s; } u;
  u.h = __float2bfloat16(f);
  return u.s;
}

// ---------------- merged prep kernel ----------------
// f <  4096  : a1 frags (16x16x32 A) of (-2*log2e)*E
// f < 12288  : eb frags (16x16x16 f16 B) of E
// f < 12800  : norms ||e_k||^2 * log2e
__global__ void prep_all(const float* __restrict__ emb, short8* __restrict__ a1,
                         half4* __restrict__ eb, float* __restrict__ norms) {
  const int f = blockIdx.x * 256 + threadIdx.x;
  if (f < 4096) {
    const int l = f & 63;
    const int s = (f >> 6) & 1;
    const int m = f >> 7;
    const int row = m * 16 + (l & 15);
    const int col0 = s * 32 + (l >> 4) * 8;
    short8 v;
    #pragma unroll
    for (int i = 0; i < 8; ++i)
      v[i] = bf16s(-2.0f * LOG2E * emb[row * 64 + col0 + i]);
    a1[f] = v;
  } else if (f < 12288) {
    const int e = f - 4096;
    const int l = e & 63;
    const int m2 = (e >> 6) & 3;
    const int kt = e >> 8;               // k-16-tile index 0..31
    const int d = m2 * 16 + (l & 15);
    const int k0 = kt * 16 + 4 * (l >> 4);
    half4 v;
    #pragma unroll
    for (int i = 0; i < 4; ++i) v[i] = (_Float16)emb[(k0 + i) * 64 + d];
    eb[e] = v;
  } else if (f < 12800) {
    const int k = f - 12288;
    float acc = 0.f;
    #pragma unroll
    for (int d = 0; d < 64; ++d) { float e = emb[k * 64 + d]; acc += e * e; }
    norms[k] = acc * LOG2E;
  }
}

// ---------------- main kernel ----------------
// 4-wave blocks, 32 shared n-columns; wave w owns k-tiles [8w, 8w+8) (k-split).
// logits(base2) = log2e*(||e_k||^2 - 2 x.e_k); ||x||^2 dropped (shift-invariant),
// |logit| tiny -> exp2 without max. matmul1 C-layout (col=l15, row=4g+r) == A-layout
// of mfma_16x16x16_f16 -> P feeds matmul2 in-register, no barriers in main loop.
// Frag loads per wave = 56 (4x less than full-K), pacc 32 + bx 16 regs ->
// 4 waves/SIMD without spill. Cross-wave Num/den reduce once at the end via LDS.
__global__ __launch_bounds__(256, 4) void vq_main(
    const float* __restrict__ x, const short8* __restrict__ a1,
    const half4* __restrict__ eb, const float* __restrict__ norms,
    float* __restrict__ out) {
  __shared__ __align__(16) char lds_raw[17408];
  short* Xl   = reinterpret_cast<short*>(lds_raw);            // [32][72] bf16 (staging)
  float* Rf   = reinterpret_cast<float*>(lds_raw);            // [4][16][66] f32 (epilogue)
  float* denl = reinterpret_cast<float*>(lds_raw + 16896);    // [4][32]

  const int t = threadIdx.x;
  const int lane = t & 63;
  const int w = t >> 6;
  const int l15 = lane & 15;
  const int g = lane >> 4;

  const int tile = blockIdx.x * 32;
  const int b = tile >> 14;
  const int off = tile & 16383;
  const float* xb = x + (size_t)b * (64 * SPW) + off;
  float* ob = out + (size_t)b * (64 * SPW) + off;

  // stage X tile: threads 0..127 each load a 4d x 4n fp32 micro-tile (coalesced
  // float4 rows), transpose in-register, write bf16 d-quads into Xl[n][d].
  if (t < 128) {
    const int n0 = 4 * (t & 7);
    const int d0 = 4 * (t >> 3);
    const float4 r0 = *reinterpret_cast<const float4*>(xb + (size_t)(d0 + 0) * SPW + n0);
    const float4 r1 = *reinterpret_cast<const float4*>(xb + (size_t)(d0 + 1) * SPW + n0);
    const float4 r2 = *reinterpret_cast<const float4*>(xb + (size_t)(d0 + 2) * SPW + n0);
    const float4 r3 = *reinterpret_cast<const float4*>(xb + (size_t)(d0 + 3) * SPW + n0);
    const short4v c0 = {bf16s(r0.x), bf16s(r1.x), bf16s(r2.x), bf16s(r3.x)};
    const short4v c1 = {bf16s(r0.y), bf16s(r1.y), bf16s(r2.y), bf16s(r3.y)};
    const short4v c2 = {bf16s(r0.z), bf16s(r1.z), bf16s(r2.z), bf16s(r3.z)};
    const short4v c3 = {bf16s(r0.w), bf16s(r1.w), bf16s(r2.w), bf16s(r3.w)};
    *reinterpret_cast<short4v*>(&Xl[(n0 + 0) * XST + d0]) = c0;
    *reinterpret_cast<short4v*>(&Xl[(n0 + 1) * XST + d0]) = c1;
    *reinterpret_cast<short4v*>(&Xl[(n0 + 2) * XST + d0]) = c2;
    *reinterpret_cast<short4v*>(&Xl[(n0 + 3) * XST + d0]) = c3;
  }
  __syncthreads();

  // bx: matmul1 B-frags, full 32-col tile, same for every wave (16 VGPRs)
  short8 bx[2][2];
  #pragma unroll
  for (int j = 0; j < 2; ++j) {
    const int base = (j * 16 + l15) * XST + g * 8;
    bx[j][0] = *reinterpret_cast<const short8*>(&Xl[base]);
    bx[j][1] = *reinterpret_cast<const short8*>(&Xl[base + 32]);
  }

  f32x4 pacc[2][4];   // [j n-tile][m2 d-tile] Num^T partial over this wave's k-slice
  #pragma unroll
  for (int j = 0; j < 2; ++j)
    #pragma unroll
    for (int m2 = 0; m2 < 4; ++m2) pacc[j][m2] = f32x4{0.f, 0.f, 0.f, 0.f};
  float denp[2] = {0.f, 0.f};

  #pragma unroll 2
  for (int q = 0; q < 8; ++q) {
    const int kt = w * 8 + q;            // this wave's k-16-tile
    const short8 a1f0 = a1[(kt * 2 + 0) * 64 + lane];
    const short8 a1f1 = a1[(kt * 2 + 1) * 64 + lane];
    const half4 e0 = eb[(kt * 4 + 0) * 64 + lane];
    const half4 e1 = eb[(kt * 4 + 1) * 64 + lane];
    const half4 e2 = eb[(kt * 4 + 2) * 64 + lane];
    const half4 e3 = eb[(kt * 4 + 3) * 64 + lane];
    const float4 nv = *reinterpret_cast<const float4*>(&norms[kt * 16 + g * 4]);
    #pragma unroll
    for (int j = 0; j < 2; ++j) {
      f32x4 z = {0.f, 0.f, 0.f, 0.f};
      z = __builtin_amdgcn_mfma_f32_16x16x32_bf16(a1f0, bx[j][0], z, 0, 0, 0);
      z = __builtin_amdgcn_mfma_f32_16x16x32_bf16(a1f1, bx[j][1], z, 0, 0, 0);
      const float p0 = exp2_hw(nv.x + z[0]);
      const float p1 = exp2_hw(nv.y + z[1]);
      const float p2 = exp2_hw(nv.z + z[2]);
      const float p3 = exp2_hw(nv.w + z[3]);
      denp[j] += (p0 + p1) + (p2 + p3);
      const half4 pa = {(_Float16)p0, (_Float16)p1, (_Float16)p2, (_Float16)p3};
      pacc[j][0] = __builtin_amdgcn_mfma_f32_16x16x16f16(pa, e0, pacc[j][0], 0, 0, 0);
      pacc[j][1] = __builtin_amdgcn_mfma_f32_16x16x16f16(pa, e1, pacc[j][1], 0, 0, 0);
      pacc[j][2] = __builtin_amdgcn_mfma_f32_16x16x16f16(pa, e2, pacc[j][2], 0, 0, 0);
      pacc[j][3] = __builtin_amdgcn_mfma_f32_16x16x16f16(pa, e3, pacc[j][3], 0, 0, 0);
    }
  }

  // den partials: reduce over lane-groups (k within slice) -> denl[w][col]
  #pragma unroll
  for (int j = 0; j < 2; ++j) {
    denp[j] += __shfl_xor(denp[j], 16, 64);
    denp[j] += __shfl_xor(denp[j], 32, 64);
  }
  if (lane < 16) {
    denl[w * 32 + l15] = denp[0];
    denl[w * 32 + 16 + l15] = denp[1];
  }

  // epilogue: sum 4 wave-partials of Num via Rf, divide by den, coalesced store
  const int n16 = t & 15;
  const int dq2 = t >> 4;
  #pragma unroll
  for (int j = 0; j < 2; ++j) {
    __syncthreads();  // j=0: denl ready + Xl dead; j=1: WAR on Rf
    #pragma unroll
    for (int m2 = 0; m2 < 4; ++m2)
      #pragma unroll
      for (int r = 0; r < 4; ++r)
        Rf[(w * 16 + 4 * g + r) * RW + m2 * 16 + l15] = pacc[j][m2][r];
    __syncthreads();
    const float den = (denl[j * 16 + n16] + denl[32 + j * 16 + n16])
                    + (denl[64 + j * 16 + n16] + denl[96 + j * 16 + n16]);
    const float rdv = 1.0f / den;
    #pragma unroll
    for (int r = 0; r < 4; ++r) {
      const int dd = r * 16 + dq2;
      const float sum = (Rf[n16 * RW + dd] + Rf[(16 + n16) * RW + dd])
                      + (Rf[(32 + n16) * RW + dd] + Rf[(48 + n16) * RW + dd]);
      ob[(size_t)dd * SPW + j * 16 + n16] = sum * rdv;
    }
  }
}

extern "C" void kernel_launch(void* const* d_in, const int* in_sizes, int n_in,
                              void* d_out, int out_size, void* d_ws, size_t ws_size,
                              hipStream_t stream) {
  (void)in_sizes; (void)n_in; (void)out_size; (void)ws_size;
  const float* x   = (const float*)d_in[0];   // (8, 64, 16, 32, 32) fp32
  const float* emb = (const float*)d_in[1];   // (512, 64) fp32
  float* out = (float*)d_out;

  char* ws = (char*)d_ws;
  short8* a1   = (short8*)ws;                 // 65536 B
  half4*  eb   = (half4*)(ws + 65536);        // 65536 B
  float*  norms = (float*)(ws + 131072);      // 2048 B

  prep_all<<<50, 256, 0, stream>>>(emb, a1, eb, norms);
  vq_main<<<4096, 256, 0, stream>>>(x, a1, eb, norms, out);
}

// Round 7
// 40.677 us; speedup vs baseline: 1.5437x; 1.1169x over previous
//
#include <hip/hip_runtime.h>
#include <hip/hip_bf16.h>

typedef __attribute__((ext_vector_type(8))) short short8;
typedef __attribute__((ext_vector_type(4))) short short4v;
typedef __attribute__((ext_vector_type(4))) _Float16 half4;
typedef __attribute__((ext_vector_type(4))) float f32x4;

#define SPW 16384   // T*H*W spatial positions per batch
#define XST 72      // Xl row stride in shorts
#define RW  67      // Rf row stride in dwords (odd -> spread banks in epilogue)
#define LOG2E 1.4426950408889634f

__device__ __forceinline__ float exp2_hw(float f) {
  return __builtin_amdgcn_exp2f(f);   // v_exp_f32 (base-2)
}

__device__ __forceinline__ short bf16s(float f) {
  union { __hip_bfloat16 h; short s; } u;
  u.h = __float2bfloat16(f);
  return u.s;
}

// ---------------- merged prep kernel ----------------
// f <  4096  : a1 frags (16x16x32 A) of (-2*log2e)*E
// f < 12288  : eb frags (16x16x16 f16 B) of E
// f < 12800  : norms ||e_k||^2 * log2e
__global__ void prep_all(const float* __restrict__ emb, short8* __restrict__ a1,
                         half4* __restrict__ eb, float* __restrict__ norms) {
  const int f = blockIdx.x * 256 + threadIdx.x;
  if (f < 4096) {
    const int l = f & 63;
    const int s = (f >> 6) & 1;
    const int m = f >> 7;
    const int row = m * 16 + (l & 15);
    const int col0 = s * 32 + (l >> 4) * 8;
    short8 v;
    #pragma unroll
    for (int i = 0; i < 8; ++i)
      v[i] = bf16s(-2.0f * LOG2E * emb[row * 64 + col0 + i]);
    a1[f] = v;
  } else if (f < 12288) {
    const int e = f - 4096;
    const int l = e & 63;
    const int m2 = (e >> 6) & 3;
    const int kt = e >> 8;               // k-16-tile index 0..31
    const int d = m2 * 16 + (l & 15);
    const int k0 = kt * 16 + 4 * (l >> 4);
    half4 v;
    #pragma unroll
    for (int i = 0; i < 4; ++i) v[i] = (_Float16)emb[(k0 + i) * 64 + d];
    eb[e] = v;
  } else if (f < 12800) {
    const int k = f - 12288;
    float acc = 0.f;
    #pragma unroll
    for (int d = 0; d < 64; ++d) { float e = emb[k * 64 + d]; acc += e * e; }
    norms[k] = acc * LOG2E;
  }
}

// ---------------- main kernel ----------------
// 4-wave blocks, 128 n-columns; wave (cg,kg) owns cols [cg*64,+64) x k [kg*256,+256).
// logits(base2) = log2e*(||e_k||^2 - 2 x.e_k); ||x||^2 dropped (shift-invariant),
// |logit| tiny -> exp2 without max. matmul1 C-layout (col=l15, row=4g+r) == A-layout
// of mfma_16x16x16_f16 -> P feeds matmul2 in-register; no barriers in main loop.
// 16 kt fully unrolled + 170-reg budget (256,3) -> scheduler pipelines frag loads.
// Epilogue: Rf LDS transpose -> 512B-contiguous stores per d-row.
__global__ __launch_bounds__(256, 3) void vq_main(
    const float* __restrict__ x, const short8* __restrict__ a1,
    const half4* __restrict__ eb, const float* __restrict__ norms,
    float* __restrict__ out) {
  __shared__ __align__(16) char lds_raw[35840];
  short* Xl   = reinterpret_cast<short*>(lds_raw);            // [128][72] bf16 (staging)
  float* Rf   = reinterpret_cast<float*>(lds_raw);            // [128][67] f32 (epilogue)
  float* denl = reinterpret_cast<float*>(lds_raw + 34304);    // [2][128]
  float* rden = reinterpret_cast<float*>(lds_raw + 35328);    // [128]

  const int t = threadIdx.x;
  const int lane = t & 63;
  const int w = t >> 6;
  const int cg = w & 1;        // column group (64 cols)
  const int kg = w >> 1;       // k group (256 k = 16 kt)
  const int l15 = lane & 15;
  const int g = lane >> 4;

  const int tile = blockIdx.x * 128;
  const int b = tile >> 14;
  const int off = tile & 16383;
  const float* xb = x + (size_t)b * (64 * SPW) + off;
  float* ob = out + (size_t)b * (64 * SPW) + off;

  // stage X tile: global [d][n] fp32 -> LDS [n][d] bf16. Thread owns a 4d x 4n
  // micro-tile per half; 16 consecutive threads x 16B = 256B contiguous per d-row.
  {
    const int n0 = 4 * (t & 15);
    const int d0 = 4 * (t >> 4);
    #pragma unroll
    for (int h = 0; h < 2; ++h) {
      const int nb = h * 64 + n0;
      const float4 r0 = *reinterpret_cast<const float4*>(xb + (size_t)(d0 + 0) * SPW + nb);
      const float4 r1 = *reinterpret_cast<const float4*>(xb + (size_t)(d0 + 1) * SPW + nb);
      const float4 r2 = *reinterpret_cast<const float4*>(xb + (size_t)(d0 + 2) * SPW + nb);
      const float4 r3 = *reinterpret_cast<const float4*>(xb + (size_t)(d0 + 3) * SPW + nb);
      const short4v c0 = {bf16s(r0.x), bf16s(r1.x), bf16s(r2.x), bf16s(r3.x)};
      const short4v c1 = {bf16s(r0.y), bf16s(r1.y), bf16s(r2.y), bf16s(r3.y)};
      const short4v c2 = {bf16s(r0.z), bf16s(r1.z), bf16s(r2.z), bf16s(r3.z)};
      const short4v c3 = {bf16s(r0.w), bf16s(r1.w), bf16s(r2.w), bf16s(r3.w)};
      *reinterpret_cast<short4v*>(&Xl[(nb + 0) * XST + d0]) = c0;
      *reinterpret_cast<short4v*>(&Xl[(nb + 1) * XST + d0]) = c1;
      *reinterpret_cast<short4v*>(&Xl[(nb + 2) * XST + d0]) = c2;
      *reinterpret_cast<short4v*>(&Xl[(nb + 3) * XST + d0]) = c3;
    }
  }
  __syncthreads();

  // bx: matmul1 B-frags for this wave's 64 columns (32 VGPR)
  short8 bx[4][2];
  #pragma unroll
  for (int j = 0; j < 4; ++j) {
    const int base = (cg * 64 + j * 16 + l15) * XST + g * 8;
    bx[j][0] = *reinterpret_cast<const short8*>(&Xl[base]);
    bx[j][1] = *reinterpret_cast<const short8*>(&Xl[base + 32]);
  }

  f32x4 pacc[4][4];   // [j n-tile][m2 d-tile] Num^T partial over this wave's k-slice
  #pragma unroll
  for (int j = 0; j < 4; ++j)
    #pragma unroll
    for (int m2 = 0; m2 < 4; ++m2) pacc[j][m2] = f32x4{0.f, 0.f, 0.f, 0.f};
  float denp[4] = {0.f, 0.f, 0.f, 0.f};

  const int kbase = kg * 16;
  #pragma unroll
  for (int q = 0; q < 16; ++q) {
    const int kt = kbase + q;            // compile-time after full unroll
    const short8 a1f0 = a1[(kt * 2 + 0) * 64 + lane];
    const short8 a1f1 = a1[(kt * 2 + 1) * 64 + lane];
    const half4 e0 = eb[(kt * 4 + 0) * 64 + lane];
    const half4 e1 = eb[(kt * 4 + 1) * 64 + lane];
    const half4 e2 = eb[(kt * 4 + 2) * 64 + lane];
    const half4 e3 = eb[(kt * 4 + 3) * 64 + lane];
    const float4 nv = *reinterpret_cast<const float4*>(&norms[kt * 16 + g * 4]);
    #pragma unroll
    for (int j = 0; j < 4; ++j) {
      f32x4 z = {0.f, 0.f, 0.f, 0.f};
      z = __builtin_amdgcn_mfma_f32_16x16x32_bf16(a1f0, bx[j][0], z, 0, 0, 0);
      z = __builtin_amdgcn_mfma_f32_16x16x32_bf16(a1f1, bx[j][1], z, 0, 0, 0);
      const float p0 = exp2_hw(nv.x + z[0]);
      const float p1 = exp2_hw(nv.y + z[1]);
      const float p2 = exp2_hw(nv.z + z[2]);
      const float p3 = exp2_hw(nv.w + z[3]);
      denp[j] += (p0 + p1) + (p2 + p3);
      const half4 pa = {(_Float16)p0, (_Float16)p1, (_Float16)p2, (_Float16)p3};
      pacc[j][0] = __builtin_amdgcn_mfma_f32_16x16x16f16(pa, e0, pacc[j][0], 0, 0, 0);
      pacc[j][1] = __builtin_amdgcn_mfma_f32_16x16x16f16(pa, e1, pacc[j][1], 0, 0, 0);
      pacc[j][2] = __builtin_amdgcn_mfma_f32_16x16x16f16(pa, e2, pacc[j][2], 0, 0, 0);
      pacc[j][3] = __builtin_amdgcn_mfma_f32_16x16x16f16(pa, e3, pacc[j][3], 0, 0, 0);
    }
  }

  // den partials: reduce over lane-groups (k within slice) -> denl[kg][col]
  #pragma unroll
  for (int j = 0; j < 4; ++j) {
    denp[j] += __shfl_xor(denp[j], 16, 64);
    denp[j] += __shfl_xor(denp[j], 32, 64);
  }
  if (lane < 16) {
    #pragma unroll
    for (int j = 0; j < 4; ++j)
      denl[kg * 128 + cg * 64 + j * 16 + l15] = denp[j];
  }

  // phase A: kg==0 waves write their Num^T partial into Rf (Xl is dead)
  if (kg == 0) {
    #pragma unroll
    for (int j = 0; j < 4; ++j)
      #pragma unroll
      for (int m2 = 0; m2 < 4; ++m2)
        #pragma unroll
        for (int r = 0; r < 4; ++r)
          Rf[(cg * 64 + j * 16 + 4 * g + r) * RW + m2 * 16 + l15] = pacc[j][m2][r];
  }
  __syncthreads();   // denl complete; phase-A Rf writes complete

  // phase B: kg==1 waves accumulate; kg==0 threads (t<128) build reciprocal den
  if (kg == 1) {
    #pragma unroll
    for (int j = 0; j < 4; ++j)
      #pragma unroll
      for (int m2 = 0; m2 < 4; ++m2)
        #pragma unroll
        for (int r = 0; r < 4; ++r)
          Rf[(cg * 64 + j * 16 + 4 * g + r) * RW + m2 * 16 + l15] += pacc[j][m2][r];
  } else {
    rden[t & 127] = 1.0f / (denl[t & 127] + denl[128 + (t & 127)]);
  }
  __syncthreads();

  // phase C: cooperative store, 512B contiguous per d-row (32 lanes x float4)
  const int nq = t & 31;
  const int n = 4 * nq;
  const int dh = t >> 5;
  #pragma unroll
  for (int it = 0; it < 8; ++it) {
    const int d = it * 8 + dh;
    const float4 o = {Rf[(n + 0) * RW + d] * rden[n + 0],
                      Rf[(n + 1) * RW + d] * rden[n + 1],
                      Rf[(n + 2) * RW + d] * rden[n + 2],
                      Rf[(n + 3) * RW + d] * rden[n + 3]};
    *reinterpret_cast<float4*>(&ob[(size_t)d * SPW + n]) = o;
  }
}

extern "C" void kernel_launch(void* const* d_in, const int* in_sizes, int n_in,
                              void* d_out, int out_size, void* d_ws, size_t ws_size,
                              hipStream_t stream) {
  (void)in_sizes; (void)n_in; (void)out_size; (void)ws_size;
  const float* x   = (const float*)d_in[0];   // (8, 64, 16, 32, 32) fp32
  const float* emb = (const float*)d_in[1];   // (512, 64) fp32
  float* out = (float*)d_out;

  char* ws = (char*)d_ws;
  short8* a1   = (short8*)ws;                 // 65536 B
  half4*  eb   = (half4*)(ws + 65536);        // 65536 B
  float*  norms = (float*)(ws + 131072);      // 2048 B

  prep_all<<<50, 256, 0, stream>>>(emb, a1, eb, norms);
  vq_main<<<1024, 256, 0, stream>>>(x, a1, eb, norms, out);
}